// Round 8
// baseline (721.011 us; speedup 1.0000x reference)
//
#include <hip/hip_runtime.h>
#include <stdint.h>

typedef __bf16 bf16x8 __attribute__((ext_vector_type(8)));
typedef float f32x4 __attribute__((ext_vector_type(4)));
typedef unsigned short ushort_t;

#define MFMA16(a,b,c) __builtin_amdgcn_mfma_f32_16x16x32_bf16((a),(b),(c),0,0,0)

__device__ __forceinline__ unsigned short f2bf(float f){
    unsigned u = __builtin_bit_cast(unsigned, f);
    u += 0x7fffu + ((u>>16)&1u);            // RNE
    return (unsigned short)(u>>16);
}
// pack two fp32 -> bf16 pair in one uint (round-half-up) — session-proven
// numerics; do NOT replace with hand-written v_cvt_pk_bf16_f32 (round-3
// post-mortem: inline-asm cvt_pk broke absmax 1.1e-3 -> 4.1e-2).
__device__ __forceinline__ unsigned pack2bf(float lo, float hi){
    unsigned a = __builtin_bit_cast(unsigned, lo) + 0x8000u;
    unsigned b = __builtin_bit_cast(unsigned, hi) + 0x8000u;
    return __builtin_amdgcn_perm(b, a, 0x07060302u);
}
__device__ __forceinline__ float bflo(unsigned u){   // low bf16 -> f32
    return __builtin_bit_cast(float, u << 16);
}
__device__ __forceinline__ float bfhi(unsigned u){   // high bf16 -> f32
    return __builtin_bit_cast(float, u & 0xffff0000u);
}
__device__ __forceinline__ float fexp2(float x){
#if __has_builtin(__builtin_amdgcn_exp2f)
    return __builtin_amdgcn_exp2f(x);       // raw v_exp_f32
#else
    return exp2f(x);
#endif
}

// async global->LDS, 16B per lane; lds = wave-uniform chunk base
__device__ __forceinline__ void async16(ushort_t* lds, const ushort_t* g){
#if __has_builtin(__builtin_amdgcn_global_load_lds)
    __builtin_amdgcn_global_load_lds(
        (const __attribute__((address_space(1))) void*)g,
        (__attribute__((address_space(3))) void*)lds, 16, 0, 0);
#else
    const int l = (int)(threadIdx.x & 63u);
    *(uint4*)(lds + (size_t)l*8) = *(const uint4*)g;
#endif
}

// ---------------------------------------------------------------------------
// Merged prep: fp32->bf16 converts (bid 0..8191), W transposes (8192..10751),
// Wo transpose (10752..11007). Block-uniform branch.
// ---------------------------------------------------------------------------
__global__ __launch_bounds__(256) void prep_all(
    const float* __restrict__ x1, const float* __restrict__ x2,
    const float* __restrict__ w0, const float* __restrict__ w1,
    const float* __restrict__ w2, const float* __restrict__ w3,
    const float* __restrict__ w4, const float* __restrict__ wo,
    ushort_t* __restrict__ Xc1, ushort_t* __restrict__ Xc2,
    ushort_t* __restrict__ Wt1, ushort_t* __restrict__ Wt2,
    ushort_t* __restrict__ Wot)
{
    __shared__ float Tb[64*33];
    const int bid = blockIdx.x;
    const int t = threadIdx.x;
    if (bid < 8192) {
        const float* src = (bid >= 4096) ? x2 : x1;
        ushort_t*    dst = (bid >= 4096) ? Xc2 : Xc1;
        size_t i = ((size_t)(bid & 4095)*256 + t)*8;
        float4 a = *(const float4*)(src + i);
        float4 b = *(const float4*)(src + i + 4);
        uint4 o;
        o.x = pack2bf(a.x, a.y); o.y = pack2bf(a.z, a.w);
        o.z = pack2bf(b.x, b.y); o.w = pack2bf(b.z, b.w);
        *(uint4*)(dst + i) = o;
    } else if (bid < 10752) {
        const int r = bid - 8192;
        const int z = r >> 9;
        const int rr = r & 511;
        const int k0 = (rr & 31)*32, n0 = (rr >> 5)*32;
        const float* src; ushort_t* dst;
        if (z < 3)  { src = (z==0)?w0:((z==1)?w1:w2); dst = Wt1 + (size_t)z*512*1024; }
        else        { src = (z==3)?w3:w4;             dst = Wt2 + (size_t)(z-3)*512*1024; }
        const int N = 512, K = 1024;
        int kr = t>>3, nc = (t&7)*4;
        float4 v = *(const float4*)(src + (size_t)(k0+kr)*N + n0 + nc);
        Tb[kr*33+nc] = v.x; Tb[kr*33+nc+1] = v.y;
        Tb[kr*33+nc+2] = v.z; Tb[kr*33+nc+3] = v.w;
        __syncthreads();
        int nr = t>>3, kc = (t&7)*4;
        uint2 o;
        o.x = pack2bf(Tb[kc*33+nr],     Tb[(kc+1)*33+nr]);
        o.y = pack2bf(Tb[(kc+2)*33+nr], Tb[(kc+3)*33+nr]);
        *(uint2*)(dst + (size_t)(n0+nr)*K + k0 + kc) = o;
    } else {
        const int r = bid - 10752;
        const int k0 = (r & 7)*64;
        const int n0 = (r >> 3)*32;
        const int kr = t>>3, nc = (t&7)*4;
#pragma unroll
        for (int hf = 0; hf < 2; ++hf){
            float4 v = *(const float4*)(wo + (size_t)(k0 + hf*32 + kr)*1024 + n0 + nc);
            Tb[(hf*32+kr)*33+nc]   = v.x; Tb[(hf*32+kr)*33+nc+1] = v.y;
            Tb[(hf*32+kr)*33+nc+2] = v.z; Tb[(hf*32+kr)*33+nc+3] = v.w;
        }
        __syncthreads();
        const int nr = t>>3, kc = (t&7)*8;
        ushort_t tmp[8];
#pragma unroll
        for (int e = 0; e < 8; ++e){
            int dp = kc + e;
            int d  = ((dp&3)<<4) | (dp>>2);   // invpi
            tmp[e] = f2bf(Tb[d*33+nr]);
        }
        *(uint4*)(Wot + (size_t)(n0+nr)*512 + k0 + kc) = *(uint4*)tmp;
    }
}

// ---------------------------------------------------------------------------
// Merged QKV GEMM (round-5 proven 128x128 / BK=32 / 2-phase; round-6's
// 256^2 8-phase port regressed 2x — do not re-attempt without full m201
// interleave).
// blockIdx.y < 12 : A=Xc1 @ Wt1 -> Q|K|Vt (koff 0)
// blockIdx.y >= 12: A=Xc2 @ Wt2 -> K|Vt   (koff 2048)
// ---------------------------------------------------------------------------
__global__ __launch_bounds__(256, 4) void qkv_gemm(
    const ushort_t* __restrict__ A1, const ushort_t* __restrict__ A2,
    const ushort_t* __restrict__ B1, const ushort_t* __restrict__ B2,
    ushort_t* __restrict__ Qp, ushort_t* __restrict__ Kp, ushort_t* __restrict__ Vtp)
{
    constexpr int KD = 1024;
    __shared__ ushort_t As[2][128][32];
    __shared__ ushort_t Bs[2][128][32];
    const int yb = blockIdx.y;
    const bool second = (yb >= 12);
    const ushort_t* A  = second ? A2 : A1;
    const ushort_t* Bt = second ? B2 : B1;
    const int n0 = (second ? (yb-12) : yb) * 128;
    const int koff = second ? 2048 : 0;
    const int sub  = second ? (1 + (n0>>9)) : (n0>>9);   // 0=Q,1=K,2=Vt

    const int t = threadIdx.x;
    const int m0 = blockIdx.x*128;
    const int w = t>>6, l = t&63;
    const int quad = l>>4, lc = l&15;
    const int wr = (w>>1)*64, wc = (w&1)*64;

    f32x4 acc[4][4] = {};

    const int crow = l>>2;          // row within 16-row chunk
    const int kseg = (l&3)*8;       // 8-elem k segment
    const ushort_t* gA0 = A  + (size_t)(m0 + w*32      + crow)*KD + kseg;
    const ushort_t* gA1 = A  + (size_t)(m0 + w*32 + 16 + crow)*KD + kseg;
    const ushort_t* gB0 = Bt + (size_t)(n0 + w*32      + crow)*KD + kseg;
    const ushort_t* gB1 = Bt + (size_t)(n0 + w*32 + 16 + crow)*KD + kseg;

    const int NK = KD/32;

    async16(&As[0][w*32][0],    gA0);
    async16(&As[0][w*32+16][0], gA1);
    async16(&Bs[0][w*32][0],    gB0);
    async16(&Bs[0][w*32+16][0], gB1);
    __syncthreads();

    for (int kk = 0; kk < NK; ++kk) {
        const int cur = kk & 1;
        if (kk + 1 < NK) {
            const int k0 = (kk+1)*32;
            const int nx = cur ^ 1;
            async16(&As[nx][w*32][0],    gA0 + k0);
            async16(&As[nx][w*32+16][0], gA1 + k0);
            async16(&Bs[nx][w*32][0],    gB0 + k0);
            async16(&Bs[nx][w*32+16][0], gB1 + k0);
        }
        bf16x8 af[4], bfv[4];
#pragma unroll
        for (int i = 0; i < 4; ++i) {
            af[i]  = *(const bf16x8*)&As[cur][wr + i*16 + lc][quad*8];
            bfv[i] = *(const bf16x8*)&Bs[cur][wc + i*16 + lc][quad*8];
        }
#pragma unroll
        for (int mt = 0; mt < 4; ++mt)
#pragma unroll
            for (int nt = 0; nt < 4; ++nt)
                acc[mt][nt] = MFMA16(af[mt], bfv[nt], acc[mt][nt]);
        __syncthreads();
    }

    // pi-permuted epilogue: lane covers d' = 4*lc + nt
    const int hh  = ((n0 + wc)>>6) & 7;
    const int dp  = 4*lc;
    const float QSC = 0.18033688011112042f;                // 0.125*log2(e)
    if (sub == 0) {
#pragma unroll
        for (int mt = 0; mt < 4; ++mt) {
            const int row = m0 + wr + mt*16 + quad*4;
            const int b = row>>11, i = row & 2047;
#pragma unroll
            for (int r = 0; r < 4; ++r) {
                uint2 o;
                o.x = pack2bf(acc[mt][0][r]*QSC, acc[mt][1][r]*QSC);
                o.y = pack2bf(acc[mt][2][r]*QSC, acc[mt][3][r]*QSC);
                *(uint2*)(Qp + ((size_t)(b*8+hh)*2048 + i + r)*64 + dp) = o;
            }
        }
    } else if (sub == 1) {
#pragma unroll
        for (int mt = 0; mt < 4; ++mt) {
            const int row = m0 + wr + mt*16 + quad*4;
            const int b = row>>11, i = row & 2047;
#pragma unroll
            for (int r = 0; r < 4; ++r) {
                uint2 o;
                o.x = pack2bf(acc[mt][0][r], acc[mt][1][r]);
                o.y = pack2bf(acc[mt][2][r], acc[mt][3][r]);
                *(uint2*)(Kp + ((size_t)(b*8+hh)*4096 + koff + i + r)*64 + dp) = o;
            }
        }
    } else {
#pragma unroll
        for (int mt = 0; mt < 4; ++mt) {
            const int row = m0 + wr + mt*16 + quad*4;
            const int b = row>>11, i = row & 2047;
            // kappa-permuted key slot (bits [4:2] of i rotate: b|a1|a0 -> a1|a0|b)
            const int ip = (i & ~28) | (((i>>2)&3)<<3) | (((i>>4)&1)<<2);
#pragma unroll
            for (int nt = 0; nt < 4; ++nt) {
                uint2 o;
                o.x = pack2bf(acc[mt][nt][0], acc[mt][nt][1]);
                o.y = pack2bf(acc[mt][nt][2], acc[mt][nt][3]);
                *(uint2*)(Vtp + ((size_t)(b*8+hh)*64 + dp + nt)*4096 + koff + ip) = o;
            }
        }
    }
}

// ---------------------------------------------------------------------------
// Output GEMM: A[M][512] @ Wot[N][512]^T + bias -> fp32 out. m97 structure.
// ---------------------------------------------------------------------------
__global__ __launch_bounds__(256, 4) void out_gemm(
    const ushort_t* __restrict__ A, const ushort_t* __restrict__ Bt,
    float* __restrict__ outF, const float* __restrict__ bias)
{
    constexpr int KD = 512;
    __shared__ ushort_t As[2][128][32];
    __shared__ ushort_t Bs[2][128][32];
    const int t = threadIdx.x;
    const int m0 = blockIdx.x*128, n0 = blockIdx.y*128;
    const int w = t>>6, l = t&63;
    const int quad = l>>4, lc = l&15;
    const int wr = (w>>1)*64, wc = (w&1)*64;

    f32x4 acc[4][4] = {};

    const int crow = l>>2;
    const int kseg = (l&3)*8;
    const ushort_t* gA0 = A  + (size_t)(m0 + w*32      + crow)*KD + kseg;
    const ushort_t* gA1 = A  + (size_t)(m0 + w*32 + 16 + crow)*KD + kseg;
    const ushort_t* gB0 = Bt + (size_t)(n0 + w*32      + crow)*KD + kseg;
    const ushort_t* gB1 = Bt + (size_t)(n0 + w*32 + 16 + crow)*KD + kseg;

    const int NK = KD/32;

    async16(&As[0][w*32][0],    gA0);
    async16(&As[0][w*32+16][0], gA1);
    async16(&Bs[0][w*32][0],    gB0);
    async16(&Bs[0][w*32+16][0], gB1);
    __syncthreads();

    for (int kk = 0; kk < NK; ++kk) {
        const int cur = kk & 1;
        if (kk + 1 < NK) {
            const int k0 = (kk+1)*32;
            const int nx = cur ^ 1;
            async16(&As[nx][w*32][0],    gA0 + k0);
            async16(&As[nx][w*32+16][0], gA1 + k0);
            async16(&Bs[nx][w*32][0],    gB0 + k0);
            async16(&Bs[nx][w*32+16][0], gB1 + k0);
        }
        bf16x8 af[4], bfv[4];
#pragma unroll
        for (int i = 0; i < 4; ++i) {
            af[i]  = *(const bf16x8*)&As[cur][wr + i*16 + lc][quad*8];
            bfv[i] = *(const bf16x8*)&Bs[cur][wc + i*16 + lc][quad*8];
        }
#pragma unroll
        for (int mt = 0; mt < 4; ++mt)
#pragma unroll
            for (int nt = 0; nt < 4; ++nt)
                acc[mt][nt] = MFMA16(af[mt], bfv[nt], acc[mt][nt]);
        __syncthreads();
    }

    float bv[4];
#pragma unroll
    for (int nt = 0; nt < 4; ++nt) bv[nt] = bias[n0 + wc + nt*16 + lc];
#pragma unroll
    for (int mt = 0; mt < 4; ++mt) {
        const int row = m0 + wr + mt*16 + quad*4;
#pragma unroll
        for (int nt = 0; nt < 4; ++nt) {
            const int col = n0 + wc + nt*16 + lc;
#pragma unroll
            for (int r = 0; r < 4; ++r)
                outF[(size_t)(row+r)*1024 + col] = acc[mt][nt][r] + bv[nt];
        }
    }
}

// ---------------------------------------------------------------------------
// Flash attention, S^T formulation, no-max softmax, 128 q/block (2 strips).
// Round-8: KVBLK 64->32 (LDS 32->16KB) + SPLIT=4 (grid 2048) -> 8 blocks/CU
// (was 4; issue-utilization ~29%, latency-bound). __launch_bounds__(256,8)
// pins VGPR <= 64 (current kernel is exactly 64). Per-key MFMA/ds/staging
// costs unchanged; 32-key P vector matches the existing kappa permutation
// exactly (one 32-key group per iteration). V tile [64][32] swizzle:
// chunk ^= (row>>1)&3 -> bank-trace: 8 spans x 8 lanes = b128 minimum,
// conflict-free. XCD-grouped block decomposition: all 64 (qt,sp) blocks of
// one bh land on one XCD (4MB K/V working set = one L2).
// ---------------------------------------------------------------------------
template<int SPLIT>
__global__ __launch_bounds__(256, 8) void flash_attn_k(
    const ushort_t* __restrict__ Q, const ushort_t* __restrict__ Kg,
    const ushort_t* __restrict__ Vt, ushort_t* __restrict__ AO,
    ushort_t* __restrict__ PA, ushort_t* __restrict__ PB, float* __restrict__ Lp)
{
    constexpr int NJT = 128 / SPLIT;     // 32-key tiles per block
    __shared__ ushort_t Ks[2][32][64];
    __shared__ ushort_t Vs[2][64][32];

    int bh, qt, sp;
    if (SPLIT > 1) {
        // XCD-local swizzle: id%8 = XCD (round-robin); 256 swz-ids per XCD;
        // each bh = 64 consecutive swz -> entirely on one XCD, 4 bh/XCD.
        const int id  = (int)blockIdx.x;              // 0..2047
        const int swz = (id & 7)*256 + (id >> 3);
        bh = swz >> 6;
        const int rem = swz & 63;
        sp = rem >> 4;
        qt = rem & 15;
    } else {
        bh = blockIdx.x; qt = blockIdx.y; sp = 0;
    }
    const int jt0 = sp * NJT;
    const int b = bh>>3, h = bh&7;
    const int t = threadIdx.x, wv = t>>6, l = t&63;
    const int quad = l>>4, lc = l&15;

    // Q fragments (B-operand), two strips; Q pre-scaled by 0.125*log2e
    const ushort_t* qbase = Q + ((size_t)bh*2048 + qt*128 + wv*16 + lc)*64;
    bf16x8 qA0 = *(const bf16x8*)(qbase + quad*8);
    bf16x8 qA1 = *(const bf16x8*)(qbase + 32 + quad*8);
    bf16x8 qB0 = *(const bf16x8*)(qbase + 64*64 + quad*8);
    bf16x8 qB1 = *(const bf16x8*)(qbase + 64*64 + 32 + quad*8);

    const ushort_t* Kb = Kg + (size_t)bh*4096*64;
    const ushort_t* Vb = Vt + (size_t)bh*64*4096;

    // staging: K tile 32x64 (1 async16/wave: 8 rows), V tile 64x32
    // (1 async16/wave: 16 rows). Source pre-swizzled, LDS dest linear.
    const int r8  = l>>3;                          // K row-in-group 0..7
    const int scK = (l&7) ^ r8;                    // K source chunk
    const ushort_t* kg = Kb + ((size_t)jt0*32 + wv*8 + r8)*64 + scK*8;
    const int r16 = l>>2;                          // V row-in-group 0..15
    const int scV = (l&3) ^ ((l>>3)&3);            // V source chunk ((r16>>1)&3)
    const ushort_t* vg = Vb + (size_t)(wv*16 + r16)*4096 + (size_t)jt0*32 + scV*8;

    // read-side XOR offsets (ushort units)
    const int swA = ((quad       ^ (lc&7)) << 3);  // K cols 0..31
    const int swB = (((quad ^ 4) ^ (lc&7)) << 3);  // K cols 32..63
    const int swV = ((quad ^ ((lc>>1)&3)) << 3);   // V chunk

    float l0 = 0.0f, l1 = 0.0f;
    f32x4 o0[4] = {}, o1[4] = {};

    // prologue: stage tile 0
    async16(&Ks[0][wv*8][0],  kg);
    async16(&Vs[0][wv*16][0], vg);
    __syncthreads();

    for (int jt = 0; jt < NJT; ++jt) {
        const int cur = jt & 1;
        if (jt + 1 < NJT) {
            const int nx = cur ^ 1;
            async16(&Ks[nx][wv*8][0],  kg + (size_t)(jt+1)*2048);  // 32 keys*64d
            async16(&Vs[nx][wv*16][0], vg + (size_t)(jt+1)*32);    // 32 keys
        }
        const ushort_t* KsC = &Ks[cur][0][0];
        const ushort_t* VsC = &Vs[cur][0][0];

        // S^T (32 keys), exp+pack immediately
        union { unsigned u[4]; bf16x8 v; } p0, p1;
        float rs0 = 0.0f, rs1 = 0.0f;
#pragma unroll
        for (int kt = 0; kt < 2; ++kt) {
            const int ro = (kt*16 + lc)*64;
            bf16x8 kf0 = *(const bf16x8*)(KsC + ro + swA);
            bf16x8 kf1 = *(const bf16x8*)(KsC + ro + swB);
            f32x4 z0 = {}, z1 = {};
            __builtin_amdgcn_s_setprio(1);
            z0 = MFMA16(kf0, qA0, z0); z0 = MFMA16(kf1, qA1, z0);
            z1 = MFMA16(kf0, qB0, z1); z1 = MFMA16(kf1, qB1, z1);
            __builtin_amdgcn_s_setprio(0);
            float a0 = fexp2(z0[0]), a1v = fexp2(z0[1]);
            float a2 = fexp2(z0[2]), a3 = fexp2(z0[3]);
            rs0 += (a0 + a1v) + (a2 + a3);
            p0.u[kt*2]   = pack2bf(a0, a1v);
            p0.u[kt*2+1] = pack2bf(a2, a3);
            float c0 = fexp2(z1[0]), c1 = fexp2(z1[1]);
            float c2 = fexp2(z1[2]), c3 = fexp2(z1[3]);
            rs1 += (c0 + c1) + (c2 + c3);
            p1.u[kt*2]   = pack2bf(c0, c1);
            p1.u[kt*2+1] = pack2bf(c2, c3);
        }
        l0 += rs0; l1 += rs1;

        // O^T accumulate (V kappa-permuted in global; one 32-key group/iter)
#pragma unroll
        for (int dt = 0; dt < 4; ++dt) {
            const int ro = (dt*16 + lc)*32;
            bf16x8 vf = *(const bf16x8*)(VsC + ro + swV);
            __builtin_amdgcn_s_setprio(1);
            o0[dt] = MFMA16(vf, p0.v, o0[dt]);
            o1[dt] = MFMA16(vf, p1.v, o1[dt]);
            __builtin_amdgcn_s_setprio(0);
        }
        __syncthreads();
    }

    // cross-quad l reduction (key groups live in different quads)
    l0 += __shfl_xor(l0, 16); l0 += __shfl_xor(l0, 32);
    l1 += __shfl_xor(l1, 16); l1 += __shfl_xor(l1, 32);
    float li0 = 1.0f / l0, li1 = 1.0f / l1;

    if (SPLIT == 1) {
        const int qA = qt*128 + wv*16 + lc;
        ushort_t* aodA = AO + ((size_t)b*2048 + qA)*512 + h*64 + quad*4;
        ushort_t* aodB = aodA + (size_t)64*512;
#pragma unroll
        for (int dt = 0; dt < 4; ++dt) {
            uint2 oa, ob;
            oa.x = pack2bf(o0[dt][0]*li0, o0[dt][1]*li0);
            oa.y = pack2bf(o0[dt][2]*li0, o0[dt][3]*li0);
            *(uint2*)(aodA + dt*16) = oa;
            ob.x = pack2bf(o1[dt][0]*li1, o1[dt][1]*li1);
            ob.y = pack2bf(o1[dt][2]*li1, o1[dt][3]*li1);
            *(uint2*)(aodB + dt*16) = ob;
        }
    } else {
        // half-normalized bf16 partials + l_half; splits 0,1 in PA, 2,3 in PB
        ushort_t* P = (sp < 2) ? (PA + (size_t)sp*4194304)
                               : (PB + (size_t)(sp-2)*4194304);
        const int bid = bh*16 + qt;                 // 0..511
        const int qrA = wv*16 + lc;                 // strip-A q row (0..63)
        const size_t pbA = ((size_t)bid*128 + qrA)*64;
        const size_t pbB = pbA + (size_t)64*64;     // strip B at qrow+64
#pragma unroll
        for (int dt = 0; dt < 4; ++dt) {
            uint2 oa, ob;
            oa.x = pack2bf(o0[dt][0]*li0, o0[dt][1]*li0);
            oa.y = pack2bf(o0[dt][2]*li0, o0[dt][3]*li0);
            *(uint2*)(P + pbA + dt*16 + quad*4) = oa;
            ob.x = pack2bf(o1[dt][0]*li1, o1[dt][1]*li1);
            ob.y = pack2bf(o1[dt][2]*li1, o1[dt][3]*li1);
            *(uint2*)(P + pbB + dt*16 + quad*4) = ob;
        }
        if (l < 16) {   // quad 0 lanes hold lc == l; l fully reduced
            Lp[((size_t)sp*512 + bid)*128 + qrA]      = l0;
            Lp[((size_t)sp*512 + bid)*128 + 64 + qrA] = l1;
        }
    }
}

// ---------------------------------------------------------------------------
// Combine 4-way split partials (bf16, half-normalized):
//   AO = sum_i w_i * O_i^n,  w_i = l_i / sum(l)   (fp32 merge, bf16 out)
// ---------------------------------------------------------------------------
__global__ __launch_bounds__(256) void combine_attn(
    const ushort_t* __restrict__ PA, const ushort_t* __restrict__ PB,
    const float* __restrict__ Lp, ushort_t* __restrict__ AO)
{
    const int bid = blockIdx.x;          // bh*16 + qt
    const int bh = bid>>4, qt = bid&15;
    const int b = bh>>3, h = bh&7;
    const int t = threadIdx.x;
    const int dcol = (t&15)*4;
    const size_t pblk = (size_t)bid*8192;
#pragma unroll
    for (int e = 0; e < 8; ++e) {
        const int qrow = e*16 + (t>>4);
        const size_t idx = pblk + (size_t)qrow*64 + dcol;
        uint2 u0 = *(const uint2*)(PA + idx);
        uint2 u1 = *(const uint2*)(PA + 4194304 + idx);
        uint2 u2 = *(const uint2*)(PB + idx);
        uint2 u3 = *(const uint2*)(PB + 4194304 + idx);
        float l0 = Lp[(size_t)(0*512 + bid)*128 + qrow];
        float l1 = Lp[(size_t)(1*512 + bid)*128 + qrow];
        float l2 = Lp[(size_t)(2*512 + bid)*128 + qrow];
        float l3 = Lp[(size_t)(3*512 + bid)*128 + qrow];
        float inv = 1.0f / (l0 + l1 + l2 + l3);
        float w0 = l0*inv, w1 = l1*inv, w2 = l2*inv, w3 = l3*inv;
        float r0 = w0*bflo(u0.x) + w1*bflo(u1.x) + w2*bflo(u2.x) + w3*bflo(u3.x);
        float r1 = w0*bfhi(u0.x) + w1*bfhi(u1.x) + w2*bfhi(u2.x) + w3*bfhi(u3.x);
        float r2 = w0*bflo(u0.y) + w1*bflo(u1.y) + w2*bflo(u2.y) + w3*bflo(u3.y);
        float r3 = w0*bfhi(u0.y) + w1*bfhi(u1.y) + w2*bfhi(u2.y) + w3*bfhi(u3.y);
        uint2 o;
        o.x = pack2bf(r0, r1);
        o.y = pack2bf(r2, r3);
        ushort_t* ao = AO + ((size_t)b*2048 + qt*128 + qrow)*512 + h*64 + dcol;
        *(uint2*)ao = o;
    }
}

// ---------------------------------------------------------------------------
extern "C" void kernel_launch(void* const* d_in, const int* in_sizes, int n_in,
                              void* d_out, int out_size, void* d_ws, size_t ws_size,
                              hipStream_t stream)
{
    const float* x1  = (const float*)d_in[0];
    const float* x2  = (const float*)d_in[1];
    const float* Wq1 = (const float*)d_in[2];
    const float* Wk1 = (const float*)d_in[3];
    const float* Wv1 = (const float*)d_in[4];
    const float* Wk2 = (const float*)d_in[5];
    const float* Wv2 = (const float*)d_in[6];
    const float* Wo  = (const float*)d_in[7];
    const float* bo  = (const float*)d_in[8];
    float* out = (float*)d_out;

    ushort_t* ws  = (ushort_t*)d_ws;
    ushort_t* Xc1 = ws;                 // 8,388,608 ush (reused: P splits 0,1)
    ushort_t* Xc2 = Xc1 + 8388608;      // 8,388,608 (reused as AO after attn)
    ushort_t* Wt1 = Xc2 + 8388608;      // 1,572,864 (dead after qkv -> L buffer)
    ushort_t* Wt2 = Wt1 + 1572864;      // 1,048,576
    ushort_t* Wot = Wt2 + 1048576;      //   524,288
    ushort_t* Qp  = Wot + 524288;       // 4,194,304
    ushort_t* Kp  = Qp  + 4194304;      // 8,388,608
    ushort_t* Vtp = Kp  + 8388608;      // 8,388,608  -> end 40,894,464 ush
    ushort_t* Pex = Vtp + 8388608;      // 8,388,608 (P splits 2,3)
    ushort_t* AOp = Xc2;

    prep_all<<<11008, 256, 0, stream>>>(x1, x2, Wq1, Wk1, Wv1, Wk2, Wv2, Wo,
                                        Xc1, Xc2, Wt1, Wt2, Wot);

    qkv_gemm<<<dim3(64,20), 256, 0, stream>>>(Xc1, Xc2, Wt1, Wt2, Qp, Kp, Vtp);

    const size_t NEED = 98566144ull;    // bytes: base 81.8MB + P23 16.8MB
    if (ws_size >= NEED) {
        ushort_t* P01 = Xc1;            // x1-bf16 dead after QKV gemms
        ushort_t* P23 = Pex;
        float*    Lf  = (float*)Wt1;    // Wt1 dead after qkv (1MB of 3MB)
        flash_attn_k<4><<<2048, 256, 0, stream>>>(Qp, Kp, Vtp, nullptr, P01, P23, Lf);
        combine_attn<<<512, 256, 0, stream>>>(P01, P23, Lf, AOp);
    } else {
        flash_attn_k<1><<<dim3(32,16), 256, 0, stream>>>(Qp, Kp, Vtp, AOp, nullptr, nullptr, nullptr);
    }

    out_gemm<<<dim3(64,8), 256, 0, stream>>>(AOp, Wot, out, bo);
}

// Round 9
// 283.170 us; speedup vs baseline: 2.5462x; 2.5462x over previous
//
#include <hip/hip_runtime.h>
#include <stdint.h>

typedef __bf16 bf16x8 __attribute__((ext_vector_type(8)));
typedef float f32x4 __attribute__((ext_vector_type(4)));
typedef unsigned short ushort_t;

#define MFMA16(a,b,c) __builtin_amdgcn_mfma_f32_16x16x32_bf16((a),(b),(c),0,0,0)

__device__ __forceinline__ unsigned short f2bf(float f){
    unsigned u = __builtin_bit_cast(unsigned, f);
    u += 0x7fffu + ((u>>16)&1u);            // RNE
    return (unsigned short)(u>>16);
}
// pack two fp32 -> bf16 pair in one uint (round-half-up) — session-proven
// numerics; do NOT replace with hand-written v_cvt_pk_bf16_f32 (round-3
// post-mortem: inline-asm cvt_pk broke absmax 1.1e-3 -> 4.1e-2).
__device__ __forceinline__ unsigned pack2bf(float lo, float hi){
    unsigned a = __builtin_bit_cast(unsigned, lo) + 0x8000u;
    unsigned b = __builtin_bit_cast(unsigned, hi) + 0x8000u;
    return __builtin_amdgcn_perm(b, a, 0x07060302u);
}
__device__ __forceinline__ float fexp2(float x){
#if __has_builtin(__builtin_amdgcn_exp2f)
    return __builtin_amdgcn_exp2f(x);       // raw v_exp_f32
#else
    return exp2f(x);
#endif
}

// async global->LDS, 16B per lane; lds = wave-uniform chunk base
__device__ __forceinline__ void async16(ushort_t* lds, const ushort_t* g){
#if __has_builtin(__builtin_amdgcn_global_load_lds)
    __builtin_amdgcn_global_load_lds(
        (const __attribute__((address_space(1))) void*)g,
        (__attribute__((address_space(3))) void*)lds, 16, 0, 0);
#else
    const int l = (int)(threadIdx.x & 63u);
    *(uint4*)(lds + (size_t)l*8) = *(const uint4*)g;
#endif
}

// ---------------------------------------------------------------------------
// Merged prep: fp32->bf16 converts (bid 0..8191), W transposes (8192..10751),
// Wo transpose (10752..11007). Block-uniform branch.
// ---------------------------------------------------------------------------
__global__ __launch_bounds__(256) void prep_all(
    const float* __restrict__ x1, const float* __restrict__ x2,
    const float* __restrict__ w0, const float* __restrict__ w1,
    const float* __restrict__ w2, const float* __restrict__ w3,
    const float* __restrict__ w4, const float* __restrict__ wo,
    ushort_t* __restrict__ Xc1, ushort_t* __restrict__ Xc2,
    ushort_t* __restrict__ Wt1, ushort_t* __restrict__ Wt2,
    ushort_t* __restrict__ Wot)
{
    __shared__ float Tb[64*33];
    const int bid = blockIdx.x;
    const int t = threadIdx.x;
    if (bid < 8192) {
        const float* src = (bid >= 4096) ? x2 : x1;
        ushort_t*    dst = (bid >= 4096) ? Xc2 : Xc1;
        size_t i = ((size_t)(bid & 4095)*256 + t)*8;
        float4 a = *(const float4*)(src + i);
        float4 b = *(const float4*)(src + i + 4);
        uint4 o;
        o.x = pack2bf(a.x, a.y); o.y = pack2bf(a.z, a.w);
        o.z = pack2bf(b.x, b.y); o.w = pack2bf(b.z, b.w);
        *(uint4*)(dst + i) = o;
    } else if (bid < 10752) {
        const int r = bid - 8192;
        const int z = r >> 9;
        const int rr = r & 511;
        const int k0 = (rr & 31)*32, n0 = (rr >> 5)*32;
        const float* src; ushort_t* dst;
        if (z < 3)  { src = (z==0)?w0:((z==1)?w1:w2); dst = Wt1 + (size_t)z*512*1024; }
        else        { src = (z==3)?w3:w4;             dst = Wt2 + (size_t)(z-3)*512*1024; }
        const int N = 512, K = 1024;
        int kr = t>>3, nc = (t&7)*4;
        float4 v = *(const float4*)(src + (size_t)(k0+kr)*N + n0 + nc);
        Tb[kr*33+nc] = v.x; Tb[kr*33+nc+1] = v.y;
        Tb[kr*33+nc+2] = v.z; Tb[kr*33+nc+3] = v.w;
        __syncthreads();
        int nr = t>>3, kc = (t&7)*4;
        uint2 o;
        o.x = pack2bf(Tb[kc*33+nr],     Tb[(kc+1)*33+nr]);
        o.y = pack2bf(Tb[(kc+2)*33+nr], Tb[(kc+3)*33+nr]);
        *(uint2*)(dst + (size_t)(n0+nr)*K + k0 + kc) = o;
    } else {
        const int r = bid - 10752;
        const int k0 = (r & 7)*64;
        const int n0 = (r >> 3)*32;
        const int kr = t>>3, nc = (t&7)*4;
#pragma unroll
        for (int hf = 0; hf < 2; ++hf){
            float4 v = *(const float4*)(wo + (size_t)(k0 + hf*32 + kr)*1024 + n0 + nc);
            Tb[(hf*32+kr)*33+nc]   = v.x; Tb[(hf*32+kr)*33+nc+1] = v.y;
            Tb[(hf*32+kr)*33+nc+2] = v.z; Tb[(hf*32+kr)*33+nc+3] = v.w;
        }
        __syncthreads();
        const int nr = t>>3, kc = (t&7)*8;
        ushort_t tmp[8];
#pragma unroll
        for (int e = 0; e < 8; ++e){
            int dp = kc + e;
            int d  = ((dp&3)<<4) | (dp>>2);   // invpi
            tmp[e] = f2bf(Tb[d*33+nr]);
        }
        *(uint4*)(Wot + (size_t)(n0+nr)*512 + k0 + kc) = *(uint4*)tmp;
    }
}

// ---------------------------------------------------------------------------
// Merged QKV GEMM: one 1280-block dispatch (round-5 proven 128x128 / BK=32 /
// 2-phase; round-6's 256^2 8-phase port regressed 2x; round-8's occupancy
// push spilled to scratch — this is the session's stable structure).
// blockIdx.y < 12 : A=Xc1 @ Wt1 -> Q|K|Vt (koff 0)
// blockIdx.y >= 12: A=Xc2 @ Wt2 -> K|Vt   (koff 2048)
// ---------------------------------------------------------------------------
__global__ __launch_bounds__(256, 4) void qkv_gemm(
    const ushort_t* __restrict__ A1, const ushort_t* __restrict__ A2,
    const ushort_t* __restrict__ B1, const ushort_t* __restrict__ B2,
    ushort_t* __restrict__ Qp, ushort_t* __restrict__ Kp, ushort_t* __restrict__ Vtp)
{
    constexpr int KD = 1024;
    __shared__ ushort_t As[2][128][32];
    __shared__ ushort_t Bs[2][128][32];
    const int yb = blockIdx.y;
    const bool second = (yb >= 12);
    const ushort_t* A  = second ? A2 : A1;
    const ushort_t* Bt = second ? B2 : B1;
    const int n0 = (second ? (yb-12) : yb) * 128;
    const int koff = second ? 2048 : 0;
    const int sub  = second ? (1 + (n0>>9)) : (n0>>9);   // 0=Q,1=K,2=Vt

    const int t = threadIdx.x;
    const int m0 = blockIdx.x*128;
    const int w = t>>6, l = t&63;
    const int quad = l>>4, lc = l&15;
    const int wr = (w>>1)*64, wc = (w&1)*64;

    f32x4 acc[4][4] = {};

    const int crow = l>>2;          // row within 16-row chunk
    const int kseg = (l&3)*8;       // 8-elem k segment
    const ushort_t* gA0 = A  + (size_t)(m0 + w*32      + crow)*KD + kseg;
    const ushort_t* gA1 = A  + (size_t)(m0 + w*32 + 16 + crow)*KD + kseg;
    const ushort_t* gB0 = Bt + (size_t)(n0 + w*32      + crow)*KD + kseg;
    const ushort_t* gB1 = Bt + (size_t)(n0 + w*32 + 16 + crow)*KD + kseg;

    const int NK = KD/32;

    async16(&As[0][w*32][0],    gA0);
    async16(&As[0][w*32+16][0], gA1);
    async16(&Bs[0][w*32][0],    gB0);
    async16(&Bs[0][w*32+16][0], gB1);
    __syncthreads();

    for (int kk = 0; kk < NK; ++kk) {
        const int cur = kk & 1;
        if (kk + 1 < NK) {
            const int k0 = (kk+1)*32;
            const int nx = cur ^ 1;
            async16(&As[nx][w*32][0],    gA0 + k0);
            async16(&As[nx][w*32+16][0], gA1 + k0);
            async16(&Bs[nx][w*32][0],    gB0 + k0);
            async16(&Bs[nx][w*32+16][0], gB1 + k0);
        }
        bf16x8 af[4], bfv[4];
#pragma unroll
        for (int i = 0; i < 4; ++i) {
            af[i]  = *(const bf16x8*)&As[cur][wr + i*16 + lc][quad*8];
            bfv[i] = *(const bf16x8*)&Bs[cur][wc + i*16 + lc][quad*8];
        }
#pragma unroll
        for (int mt = 0; mt < 4; ++mt)
#pragma unroll
            for (int nt = 0; nt < 4; ++nt)
                acc[mt][nt] = MFMA16(af[mt], bfv[nt], acc[mt][nt]);
        __syncthreads();
    }

    // pi-permuted epilogue: lane covers d' = 4*lc + nt
    const int hh  = ((n0 + wc)>>6) & 7;
    const int dp  = 4*lc;
    const float QSC = 0.18033688011112042f;                // 0.125*log2(e)
    if (sub == 0) {
#pragma unroll
        for (int mt = 0; mt < 4; ++mt) {
            const int row = m0 + wr + mt*16 + quad*4;
            const int b = row>>11, i = row & 2047;
#pragma unroll
            for (int r = 0; r < 4; ++r) {
                uint2 o;
                o.x = pack2bf(acc[mt][0][r]*QSC, acc[mt][1][r]*QSC);
                o.y = pack2bf(acc[mt][2][r]*QSC, acc[mt][3][r]*QSC);
                *(uint2*)(Qp + ((size_t)(b*8+hh)*2048 + i + r)*64 + dp) = o;
            }
        }
    } else if (sub == 1) {
#pragma unroll
        for (int mt = 0; mt < 4; ++mt) {
            const int row = m0 + wr + mt*16 + quad*4;
            const int b = row>>11, i = row & 2047;
#pragma unroll
            for (int r = 0; r < 4; ++r) {
                uint2 o;
                o.x = pack2bf(acc[mt][0][r], acc[mt][1][r]);
                o.y = pack2bf(acc[mt][2][r], acc[mt][3][r]);
                *(uint2*)(Kp + ((size_t)(b*8+hh)*4096 + koff + i + r)*64 + dp) = o;
            }
        }
    } else {
#pragma unroll
        for (int mt = 0; mt < 4; ++mt) {
            const int row = m0 + wr + mt*16 + quad*4;
            const int b = row>>11, i = row & 2047;
            // kappa-permuted key slot (bits [4:2] of i rotate: b|a1|a0 -> a1|a0|b)
            const int ip = (i & ~28) | (((i>>2)&3)<<3) | (((i>>4)&1)<<2);
#pragma unroll
            for (int nt = 0; nt < 4; ++nt) {
                uint2 o;
                o.x = pack2bf(acc[mt][nt][0], acc[mt][nt][1]);
                o.y = pack2bf(acc[mt][nt][2], acc[mt][nt][3]);
                *(uint2*)(Vtp + ((size_t)(b*8+hh)*64 + dp + nt)*4096 + koff + ip) = o;
            }
        }
    }
}

// ---------------------------------------------------------------------------
// Output GEMM: A[M][512] @ Wot[N][512]^T + bias -> fp32 out. m97 structure.
// ---------------------------------------------------------------------------
__global__ __launch_bounds__(256, 4) void out_gemm(
    const ushort_t* __restrict__ A, const ushort_t* __restrict__ Bt,
    float* __restrict__ outF, const float* __restrict__ bias)
{
    constexpr int KD = 512;
    __shared__ ushort_t As[2][128][32];
    __shared__ ushort_t Bs[2][128][32];
    const int t = threadIdx.x;
    const int m0 = blockIdx.x*128, n0 = blockIdx.y*128;
    const int w = t>>6, l = t&63;
    const int quad = l>>4, lc = l&15;
    const int wr = (w>>1)*64, wc = (w&1)*64;

    f32x4 acc[4][4] = {};

    const int crow = l>>2;
    const int kseg = (l&3)*8;
    const ushort_t* gA0 = A  + (size_t)(m0 + w*32      + crow)*KD + kseg;
    const ushort_t* gA1 = A  + (size_t)(m0 + w*32 + 16 + crow)*KD + kseg;
    const ushort_t* gB0 = Bt + (size_t)(n0 + w*32      + crow)*KD + kseg;
    const ushort_t* gB1 = Bt + (size_t)(n0 + w*32 + 16 + crow)*KD + kseg;

    const int NK = KD/32;

    async16(&As[0][w*32][0],    gA0);
    async16(&As[0][w*32+16][0], gA1);
    async16(&Bs[0][w*32][0],    gB0);
    async16(&Bs[0][w*32+16][0], gB1);
    __syncthreads();

    for (int kk = 0; kk < NK; ++kk) {
        const int cur = kk & 1;
        if (kk + 1 < NK) {
            const int k0 = (kk+1)*32;
            const int nx = cur ^ 1;
            async16(&As[nx][w*32][0],    gA0 + k0);
            async16(&As[nx][w*32+16][0], gA1 + k0);
            async16(&Bs[nx][w*32][0],    gB0 + k0);
            async16(&Bs[nx][w*32+16][0], gB1 + k0);
        }
        bf16x8 af[4], bfv[4];
#pragma unroll
        for (int i = 0; i < 4; ++i) {
            af[i]  = *(const bf16x8*)&As[cur][wr + i*16 + lc][quad*8];
            bfv[i] = *(const bf16x8*)&Bs[cur][wc + i*16 + lc][quad*8];
        }
#pragma unroll
        for (int mt = 0; mt < 4; ++mt)
#pragma unroll
            for (int nt = 0; nt < 4; ++nt)
                acc[mt][nt] = MFMA16(af[mt], bfv[nt], acc[mt][nt]);
        __syncthreads();
    }

    float bv[4];
#pragma unroll
    for (int nt = 0; nt < 4; ++nt) bv[nt] = bias[n0 + wc + nt*16 + lc];
#pragma unroll
    for (int mt = 0; mt < 4; ++mt) {
        const int row = m0 + wr + mt*16 + quad*4;
#pragma unroll
        for (int nt = 0; nt < 4; ++nt) {
            const int col = n0 + wc + nt*16 + lc;
#pragma unroll
            for (int r = 0; r < 4; ++r)
                outF[(size_t)(row+r)*1024 + col] = acc[mt][nt][r] + bv[nt];
        }
    }
}

// ---------------------------------------------------------------------------
// Flash attention, S^T formulation, no-max softmax, 128 q/block (2 strips).
// Proven round-4/5 configuration: KVBLK=64, SPLIT=2, launch_bounds(256,4)
// (natural VGPR=64, occ 31.5%, 0 bank conflicts, 87us). Round-8 post-mortem:
// do NOT force (256,8) — the 64-VGPR cap spills o0/o1 to scratch
// (FETCH 20MB->990MB, 6x slower).
// ---------------------------------------------------------------------------
template<int SPLIT>
__global__ __launch_bounds__(256, 4) void flash_attn_k(
    const ushort_t* __restrict__ Q, const ushort_t* __restrict__ Kg,
    const ushort_t* __restrict__ Vt, ushort_t* __restrict__ AO,
    float* __restrict__ P0, float* __restrict__ P1, float* __restrict__ Lp)
{
    constexpr int NJT = 64 / SPLIT;
    __shared__ ushort_t Ks[2][64][64];
    __shared__ ushort_t Vs[2][64][64];
    const int bh = blockIdx.x, qt = blockIdx.y;
    const int sp = (SPLIT > 1) ? (int)blockIdx.z : 0;
    const int jt0 = sp * NJT;
    const int b = bh>>3, h = bh&7;
    const int t = threadIdx.x, wv = t>>6, l = t&63;
    const int quad = l>>4, lc = l&15;

    const ushort_t* qbase = Q + ((size_t)bh*2048 + qt*128 + wv*16 + lc)*64;
    bf16x8 qA0 = *(const bf16x8*)(qbase + quad*8);
    bf16x8 qA1 = *(const bf16x8*)(qbase + 32 + quad*8);
    bf16x8 qB0 = *(const bf16x8*)(qbase + 64*64 + quad*8);
    bf16x8 qB1 = *(const bf16x8*)(qbase + 64*64 + 32 + quad*8);

    const ushort_t* Kb = Kg + (size_t)bh*4096*64;
    const ushort_t* Vb = Vt + (size_t)bh*64*4096;

    const int r8 = l>>3;
    const int sc = (l&7) ^ r8;
    const ushort_t* kg0 = Kb + ((size_t)jt0*64 + wv*16 + r8)*64 + sc*8;
    const ushort_t* kg1 = kg0 + (size_t)8*64;
    const ushort_t* vg0 = Vb + (size_t)(wv*16 + r8)*4096 + (size_t)jt0*64 + sc*8;
    const ushort_t* vg1 = vg0 + (size_t)8*4096;

    const int swA = ((quad       ^ (lc&7)) << 3);
    const int swB = (((quad ^ 4) ^ (lc&7)) << 3);

    float l0 = 0.0f, l1 = 0.0f;
    f32x4 o0[4] = {}, o1[4] = {};

    async16(&Ks[0][wv*16][0],   kg0);
    async16(&Ks[0][wv*16+8][0], kg1);
    async16(&Vs[0][wv*16][0],   vg0);
    async16(&Vs[0][wv*16+8][0], vg1);
    __syncthreads();

    for (int jt = 0; jt < NJT; ++jt) {
        const int cur = jt & 1;
        if (jt + 1 < NJT) {
            const int nx = cur ^ 1;
            const size_t ko = (size_t)(jt+1)*4096;
            const size_t vo = (size_t)(jt+1)*64;
            async16(&Ks[nx][wv*16][0],   kg0 + ko);
            async16(&Ks[nx][wv*16+8][0], kg1 + ko);
            async16(&Vs[nx][wv*16][0],   vg0 + vo);
            async16(&Vs[nx][wv*16+8][0], vg1 + vo);
        }
        const ushort_t* KsC = &Ks[cur][0][0];
        const ushort_t* VsC = &Vs[cur][0][0];

        union { unsigned u[8]; bf16x8 v[2]; } p0, p1;
        float rs0 = 0.0f, rs1 = 0.0f;
#pragma unroll
        for (int kt = 0; kt < 4; ++kt) {
            const int ro = (kt*16 + lc)*64;
            bf16x8 kf0 = *(const bf16x8*)(KsC + ro + swA);
            bf16x8 kf1 = *(const bf16x8*)(KsC + ro + swB);
            f32x4 z0 = {}, z1 = {};
            __builtin_amdgcn_s_setprio(1);
            z0 = MFMA16(kf0, qA0, z0); z0 = MFMA16(kf1, qA1, z0);
            z1 = MFMA16(kf0, qB0, z1); z1 = MFMA16(kf1, qB1, z1);
            __builtin_amdgcn_s_setprio(0);
            float a0 = fexp2(z0[0]), a1v = fexp2(z0[1]);
            float a2 = fexp2(z0[2]), a3 = fexp2(z0[3]);
            rs0 += (a0 + a1v) + (a2 + a3);
            p0.u[kt*2]   = pack2bf(a0, a1v);
            p0.u[kt*2+1] = pack2bf(a2, a3);
            float c0 = fexp2(z1[0]), c1 = fexp2(z1[1]);
            float c2 = fexp2(z1[2]), c3 = fexp2(z1[3]);
            rs1 += (c0 + c1) + (c2 + c3);
            p1.u[kt*2]   = pack2bf(c0, c1);
            p1.u[kt*2+1] = pack2bf(c2, c3);
        }
        l0 += rs0; l1 += rs1;

#pragma unroll
        for (int dt = 0; dt < 4; ++dt) {
            const int ro = (dt*16 + lc)*64;
            bf16x8 vf0 = *(const bf16x8*)(VsC + ro + swA);
            bf16x8 vf1 = *(const bf16x8*)(VsC + ro + swB);
            __builtin_amdgcn_s_setprio(1);
            o0[dt] = MFMA16(vf0, p0.v[0], o0[dt]);
            o0[dt] = MFMA16(vf1, p0.v[1], o0[dt]);
            o1[dt] = MFMA16(vf0, p1.v[0], o1[dt]);
            o1[dt] = MFMA16(vf1, p1.v[1], o1[dt]);
            __builtin_amdgcn_s_setprio(0);
        }
        __syncthreads();
    }

    l0 += __shfl_xor(l0, 16); l0 += __shfl_xor(l0, 32);
    l1 += __shfl_xor(l1, 16); l1 += __shfl_xor(l1, 32);

    if (SPLIT == 1) {
        float li0 = 1.0f / l0, li1 = 1.0f / l1;
        const int qA = qt*128 + wv*16 + lc;
        ushort_t* aodA = AO + ((size_t)b*2048 + qA)*512 + h*64 + quad*4;
        ushort_t* aodB = aodA + (size_t)64*512;
#pragma unroll
        for (int dt = 0; dt < 4; ++dt) {
            uint2 oa, ob;
            oa.x = pack2bf(o0[dt][0]*li0, o0[dt][1]*li0);
            oa.y = pack2bf(o0[dt][2]*li0, o0[dt][3]*li0);
            *(uint2*)(aodA + dt*16) = oa;
            ob.x = pack2bf(o1[dt][0]*li1, o1[dt][1]*li1);
            ob.y = pack2bf(o1[dt][2]*li1, o1[dt][3]*li1);
            *(uint2*)(aodB + dt*16) = ob;
        }
    } else {
        // partial epilogue: unnormalized fp32 O + l, per split half
        float* P = sp ? P1 : P0;
        const int bid = bh*16 + qt;                 // 0..511
        const int qrA = wv*16 + lc;                 // strip-A q row (0..63)
        const size_t pbA = ((size_t)bid*128 + qrA)*64;
        const size_t pbB = pbA + (size_t)64*64;     // strip B at qrow+64
#pragma unroll
        for (int dt = 0; dt < 4; ++dt) {
            *(f32x4*)(P + pbA + dt*16 + quad*4) = o0[dt];
            *(f32x4*)(P + pbB + dt*16 + quad*4) = o1[dt];
        }
        if (l < 16) {   // quad 0 lanes hold lc == l; l fully reduced
            Lp[((size_t)sp*512 + bid)*128 + qrA]      = l0;
            Lp[((size_t)sp*512 + bid)*128 + 64 + qrA] = l1;
        }
    }
}

// ---------------------------------------------------------------------------
// Combine split-K partials: AO = (P0 + P1) / (l0 + l1), bf16, pi-permuted
// layout identical to the SPLIT==1 epilogue. 512 blocks x 256 thr, 8 steps.
// ---------------------------------------------------------------------------
__global__ __launch_bounds__(256) void combine_attn(
    const float* __restrict__ P0, const float* __restrict__ P1,
    const float* __restrict__ Lp, ushort_t* __restrict__ AO)
{
    const int bid = blockIdx.x;          // bh*16 + qt
    const int bh = bid>>4, qt = bid&15;
    const int b = bh>>3, h = bh&7;
    const int t = threadIdx.x;
    const int dcol = (t&15)*4;
    const size_t pblk = (size_t)bid*8192;
#pragma unroll
    for (int e = 0; e < 8; ++e) {
        const int qrow = e*16 + (t>>4);
        const size_t idx = pblk + (size_t)qrow*64 + dcol;
        float4 a = *(const float4*)(P0 + idx);
        float4 c = *(const float4*)(P1 + idx);
        float ls = Lp[(size_t)bid*128 + qrow] + Lp[(size_t)(512 + bid)*128 + qrow];
        float inv = 1.0f / ls;
        uint2 o;
        o.x = pack2bf((a.x + c.x)*inv, (a.y + c.y)*inv);
        o.y = pack2bf((a.z + c.z)*inv, (a.w + c.w)*inv);
        ushort_t* ao = AO + ((size_t)b*2048 + qt*128 + qrow)*512 + h*64 + dcol;
        *(uint2*)ao = o;
    }
}

// ---------------------------------------------------------------------------
extern "C" void kernel_launch(void* const* d_in, const int* in_sizes, int n_in,
                              void* d_out, int out_size, void* d_ws, size_t ws_size,
                              hipStream_t stream)
{
    const float* x1  = (const float*)d_in[0];
    const float* x2  = (const float*)d_in[1];
    const float* Wq1 = (const float*)d_in[2];
    const float* Wk1 = (const float*)d_in[3];
    const float* Wv1 = (const float*)d_in[4];
    const float* Wk2 = (const float*)d_in[5];
    const float* Wv2 = (const float*)d_in[6];
    const float* Wo  = (const float*)d_in[7];
    const float* bo  = (const float*)d_in[8];
    float* out = (float*)d_out;

    ushort_t* ws  = (ushort_t*)d_ws;
    ushort_t* Xc1 = ws;                 // 8,388,608 (reused as P0 during attn)
    ushort_t* Xc2 = Xc1 + 8388608;      // 8,388,608 (reused as AO after attn)
    ushort_t* Wt1 = Xc2 + 8388608;      // 1,572,864
    ushort_t* Wt2 = Wt1 + 1572864;      // 1,048,576
    ushort_t* Wot = Wt2 + 1048576;      //   524,288
    ushort_t* Qp  = Wot + 524288;       // 4,194,304
    ushort_t* Kp  = Qp  + 4194304;      // 8,388,608
    ushort_t* Vtp = Kp  + 8388608;      // 8,388,608  -> end 40,894,464 ush
    ushort_t* Pex = Vtp + 8388608;      // 8,388,608  (P1, fp32 16.8MB)
    ushort_t* Lex = Pex + 8388608;      //   262,144  (L, fp32 512KB)
    ushort_t* AOp = Xc2;

    prep_all<<<11008, 256, 0, stream>>>(x1, x2, Wq1, Wk1, Wv1, Wk2, Wv2, Wo,
                                        Xc1, Xc2, Wt1, Wt2, Wot);

    qkv_gemm<<<dim3(64,20), 256, 0, stream>>>(Xc1, Xc2, Wt1, Wt2, Qp, Kp, Vtp);

    const size_t NEED = 99090432ull;    // bytes: base 81.8MB + P1 16.8MB + L 0.5MB
    if (ws_size >= NEED) {
        float* P0f = (float*)Xc1;       // x1-bf16 dead after QKV gemms
        float* P1f = (float*)Pex;
        float* Lf  = (float*)Lex;
        flash_attn_k<2><<<dim3(32,16,2), 256, 0, stream>>>(Qp, Kp, Vtp, nullptr, P0f, P1f, Lf);
        combine_attn<<<512, 256, 0, stream>>>(P0f, P1f, Lf, AOp);
    } else {
        flash_attn_k<1><<<dim3(32,16,1), 256, 0, stream>>>(Qp, Kp, Vtp, AOp, nullptr, nullptr, nullptr);
    }

    out_gemm<<<dim3(64,8), 256, 0, stream>>>(AOp, Wot, out, bo);
}

// Round 10
// 279.568 us; speedup vs baseline: 2.5790x; 1.0129x over previous
//
#include <hip/hip_runtime.h>
#include <stdint.h>

typedef __bf16 bf16x8 __attribute__((ext_vector_type(8)));
typedef float f32x4 __attribute__((ext_vector_type(4)));
typedef unsigned short ushort_t;

#define MFMA16(a,b,c) __builtin_amdgcn_mfma_f32_16x16x32_bf16((a),(b),(c),0,0,0)

__device__ __forceinline__ unsigned short f2bf(float f){
    unsigned u = __builtin_bit_cast(unsigned, f);
    u += 0x7fffu + ((u>>16)&1u);            // RNE
    return (unsigned short)(u>>16);
}
// pack two fp32 -> bf16 pair in one uint (round-half-up) — session-proven
// numerics; do NOT replace with hand-written v_cvt_pk_bf16_f32 (round-3
// post-mortem: inline-asm cvt_pk broke absmax 1.1e-3 -> 4.1e-2).
__device__ __forceinline__ unsigned pack2bf(float lo, float hi){
    unsigned a = __builtin_bit_cast(unsigned, lo) + 0x8000u;
    unsigned b = __builtin_bit_cast(unsigned, hi) + 0x8000u;
    return __builtin_amdgcn_perm(b, a, 0x07060302u);
}
__device__ __forceinline__ float bflo(unsigned u){   // low bf16 -> f32
    return __builtin_bit_cast(float, u << 16);
}
__device__ __forceinline__ float bfhi(unsigned u){   // high bf16 -> f32
    return __builtin_bit_cast(float, u & 0xffff0000u);
}
__device__ __forceinline__ float fexp2(float x){
#if __has_builtin(__builtin_amdgcn_exp2f)
    return __builtin_amdgcn_exp2f(x);       // raw v_exp_f32
#else
    return exp2f(x);
#endif
}

// async global->LDS, 16B per lane; lds = wave-uniform chunk base
__device__ __forceinline__ void async16(ushort_t* lds, const ushort_t* g){
#if __has_builtin(__builtin_amdgcn_global_load_lds)
    __builtin_amdgcn_global_load_lds(
        (const __attribute__((address_space(1))) void*)g,
        (__attribute__((address_space(3))) void*)lds, 16, 0, 0);
#else
    const int l = (int)(threadIdx.x & 63u);
    *(uint4*)(lds + (size_t)l*8) = *(const uint4*)g;
#endif
}

// ---------------------------------------------------------------------------
// Merged prep: fp32->bf16 converts (bid 0..8191), W transposes (8192..10751),
// Wo transpose (10752..11007). Block-uniform branch.
// ---------------------------------------------------------------------------
__global__ __launch_bounds__(256) void prep_all(
    const float* __restrict__ x1, const float* __restrict__ x2,
    const float* __restrict__ w0, const float* __restrict__ w1,
    const float* __restrict__ w2, const float* __restrict__ w3,
    const float* __restrict__ w4, const float* __restrict__ wo,
    ushort_t* __restrict__ Xc1, ushort_t* __restrict__ Xc2,
    ushort_t* __restrict__ Wt1, ushort_t* __restrict__ Wt2,
    ushort_t* __restrict__ Wot)
{
    __shared__ float Tb[64*33];
    const int bid = blockIdx.x;
    const int t = threadIdx.x;
    if (bid < 8192) {
        const float* src = (bid >= 4096) ? x2 : x1;
        ushort_t*    dst = (bid >= 4096) ? Xc2 : Xc1;
        size_t i = ((size_t)(bid & 4095)*256 + t)*8;
        float4 a = *(const float4*)(src + i);
        float4 b = *(const float4*)(src + i + 4);
        uint4 o;
        o.x = pack2bf(a.x, a.y); o.y = pack2bf(a.z, a.w);
        o.z = pack2bf(b.x, b.y); o.w = pack2bf(b.z, b.w);
        *(uint4*)(dst + i) = o;
    } else if (bid < 10752) {
        const int r = bid - 8192;
        const int z = r >> 9;
        const int rr = r & 511;
        const int k0 = (rr & 31)*32, n0 = (rr >> 5)*32;
        const float* src; ushort_t* dst;
        if (z < 3)  { src = (z==0)?w0:((z==1)?w1:w2); dst = Wt1 + (size_t)z*512*1024; }
        else        { src = (z==3)?w3:w4;             dst = Wt2 + (size_t)(z-3)*512*1024; }
        const int N = 512, K = 1024;
        int kr = t>>3, nc = (t&7)*4;
        float4 v = *(const float4*)(src + (size_t)(k0+kr)*N + n0 + nc);
        Tb[kr*33+nc] = v.x; Tb[kr*33+nc+1] = v.y;
        Tb[kr*33+nc+2] = v.z; Tb[kr*33+nc+3] = v.w;
        __syncthreads();
        int nr = t>>3, kc = (t&7)*4;
        uint2 o;
        o.x = pack2bf(Tb[kc*33+nr],     Tb[(kc+1)*33+nr]);
        o.y = pack2bf(Tb[(kc+2)*33+nr], Tb[(kc+3)*33+nr]);
        *(uint2*)(dst + (size_t)(n0+nr)*K + k0 + kc) = o;
    } else {
        const int r = bid - 10752;
        const int k0 = (r & 7)*64;
        const int n0 = (r >> 3)*32;
        const int kr = t>>3, nc = (t&7)*4;
#pragma unroll
        for (int hf = 0; hf < 2; ++hf){
            float4 v = *(const float4*)(wo + (size_t)(k0 + hf*32 + kr)*1024 + n0 + nc);
            Tb[(hf*32+kr)*33+nc]   = v.x; Tb[(hf*32+kr)*33+nc+1] = v.y;
            Tb[(hf*32+kr)*33+nc+2] = v.z; Tb[(hf*32+kr)*33+nc+3] = v.w;
        }
        __syncthreads();
        const int nr = t>>3, kc = (t&7)*8;
        ushort_t tmp[8];
#pragma unroll
        for (int e = 0; e < 8; ++e){
            int dp = kc + e;
            int d  = ((dp&3)<<4) | (dp>>2);   // invpi
            tmp[e] = f2bf(Tb[d*33+nr]);
        }
        *(uint4*)(Wot + (size_t)(n0+nr)*512 + k0 + kc) = *(uint4*)tmp;
    }
}

// ---------------------------------------------------------------------------
// Merged QKV GEMM: one 1280-block dispatch (round-5 proven 128x128 / BK=32 /
// 2-phase; round-6's 256^2 8-phase port regressed 2x; round-8's occupancy
// push spilled to scratch — this is the session's stable structure).
// blockIdx.y < 12 : A=Xc1 @ Wt1 -> Q|K|Vt (koff 0)
// blockIdx.y >= 12: A=Xc2 @ Wt2 -> K|Vt   (koff 2048)
// ---------------------------------------------------------------------------
__global__ __launch_bounds__(256, 4) void qkv_gemm(
    const ushort_t* __restrict__ A1, const ushort_t* __restrict__ A2,
    const ushort_t* __restrict__ B1, const ushort_t* __restrict__ B2,
    ushort_t* __restrict__ Qp, ushort_t* __restrict__ Kp, ushort_t* __restrict__ Vtp)
{
    constexpr int KD = 1024;
    __shared__ ushort_t As[2][128][32];
    __shared__ ushort_t Bs[2][128][32];
    const int yb = blockIdx.y;
    const bool second = (yb >= 12);
    const ushort_t* A  = second ? A2 : A1;
    const ushort_t* Bt = second ? B2 : B1;
    const int n0 = (second ? (yb-12) : yb) * 128;
    const int koff = second ? 2048 : 0;
    const int sub  = second ? (1 + (n0>>9)) : (n0>>9);   // 0=Q,1=K,2=Vt

    const int t = threadIdx.x;
    const int m0 = blockIdx.x*128;
    const int w = t>>6, l = t&63;
    const int quad = l>>4, lc = l&15;
    const int wr = (w>>1)*64, wc = (w&1)*64;

    f32x4 acc[4][4] = {};

    const int crow = l>>2;          // row within 16-row chunk
    const int kseg = (l&3)*8;       // 8-elem k segment
    const ushort_t* gA0 = A  + (size_t)(m0 + w*32      + crow)*KD + kseg;
    const ushort_t* gA1 = A  + (size_t)(m0 + w*32 + 16 + crow)*KD + kseg;
    const ushort_t* gB0 = Bt + (size_t)(n0 + w*32      + crow)*KD + kseg;
    const ushort_t* gB1 = Bt + (size_t)(n0 + w*32 + 16 + crow)*KD + kseg;

    const int NK = KD/32;

    async16(&As[0][w*32][0],    gA0);
    async16(&As[0][w*32+16][0], gA1);
    async16(&Bs[0][w*32][0],    gB0);
    async16(&Bs[0][w*32+16][0], gB1);
    __syncthreads();

    for (int kk = 0; kk < NK; ++kk) {
        const int cur = kk & 1;
        if (kk + 1 < NK) {
            const int k0 = (kk+1)*32;
            const int nx = cur ^ 1;
            async16(&As[nx][w*32][0],    gA0 + k0);
            async16(&As[nx][w*32+16][0], gA1 + k0);
            async16(&Bs[nx][w*32][0],    gB0 + k0);
            async16(&Bs[nx][w*32+16][0], gB1 + k0);
        }
        bf16x8 af[4], bfv[4];
#pragma unroll
        for (int i = 0; i < 4; ++i) {
            af[i]  = *(const bf16x8*)&As[cur][wr + i*16 + lc][quad*8];
            bfv[i] = *(const bf16x8*)&Bs[cur][wc + i*16 + lc][quad*8];
        }
#pragma unroll
        for (int mt = 0; mt < 4; ++mt)
#pragma unroll
            for (int nt = 0; nt < 4; ++nt)
                acc[mt][nt] = MFMA16(af[mt], bfv[nt], acc[mt][nt]);
        __syncthreads();
    }

    // pi-permuted epilogue: lane covers d' = 4*lc + nt
    const int hh  = ((n0 + wc)>>6) & 7;
    const int dp  = 4*lc;
    const float QSC = 0.18033688011112042f;                // 0.125*log2(e)
    if (sub == 0) {
#pragma unroll
        for (int mt = 0; mt < 4; ++mt) {
            const int row = m0 + wr + mt*16 + quad*4;
            const int b = row>>11, i = row & 2047;
#pragma unroll
            for (int r = 0; r < 4; ++r) {
                uint2 o;
                o.x = pack2bf(acc[mt][0][r]*QSC, acc[mt][1][r]*QSC);
                o.y = pack2bf(acc[mt][2][r]*QSC, acc[mt][3][r]*QSC);
                *(uint2*)(Qp + ((size_t)(b*8+hh)*2048 + i + r)*64 + dp) = o;
            }
        }
    } else if (sub == 1) {
#pragma unroll
        for (int mt = 0; mt < 4; ++mt) {
            const int row = m0 + wr + mt*16 + quad*4;
            const int b = row>>11, i = row & 2047;
#pragma unroll
            for (int r = 0; r < 4; ++r) {
                uint2 o;
                o.x = pack2bf(acc[mt][0][r], acc[mt][1][r]);
                o.y = pack2bf(acc[mt][2][r], acc[mt][3][r]);
                *(uint2*)(Kp + ((size_t)(b*8+hh)*4096 + koff + i + r)*64 + dp) = o;
            }
        }
    } else {
#pragma unroll
        for (int mt = 0; mt < 4; ++mt) {
            const int row = m0 + wr + mt*16 + quad*4;
            const int b = row>>11, i = row & 2047;
            // kappa-permuted key slot (bits [4:2] of i rotate: b|a1|a0 -> a1|a0|b)
            const int ip = (i & ~28) | (((i>>2)&3)<<3) | (((i>>4)&1)<<2);
#pragma unroll
            for (int nt = 0; nt < 4; ++nt) {
                uint2 o;
                o.x = pack2bf(acc[mt][nt][0], acc[mt][nt][1]);
                o.y = pack2bf(acc[mt][nt][2], acc[mt][nt][3]);
                *(uint2*)(Vtp + ((size_t)(b*8+hh)*64 + dp + nt)*4096 + koff + ip) = o;
            }
        }
    }
}

// ---------------------------------------------------------------------------
// Output GEMM: A[M][512] @ Wot[N][512]^T + bias -> fp32 out. m97 structure.
// ---------------------------------------------------------------------------
__global__ __launch_bounds__(256, 4) void out_gemm(
    const ushort_t* __restrict__ A, const ushort_t* __restrict__ Bt,
    float* __restrict__ outF, const float* __restrict__ bias)
{
    constexpr int KD = 512;
    __shared__ ushort_t As[2][128][32];
    __shared__ ushort_t Bs[2][128][32];
    const int t = threadIdx.x;
    const int m0 = blockIdx.x*128, n0 = blockIdx.y*128;
    const int w = t>>6, l = t&63;
    const int quad = l>>4, lc = l&15;
    const int wr = (w>>1)*64, wc = (w&1)*64;

    f32x4 acc[4][4] = {};

    const int crow = l>>2;
    const int kseg = (l&3)*8;
    const ushort_t* gA0 = A  + (size_t)(m0 + w*32      + crow)*KD + kseg;
    const ushort_t* gA1 = A  + (size_t)(m0 + w*32 + 16 + crow)*KD + kseg;
    const ushort_t* gB0 = Bt + (size_t)(n0 + w*32      + crow)*KD + kseg;
    const ushort_t* gB1 = Bt + (size_t)(n0 + w*32 + 16 + crow)*KD + kseg;

    const int NK = KD/32;

    async16(&As[0][w*32][0],    gA0);
    async16(&As[0][w*32+16][0], gA1);
    async16(&Bs[0][w*32][0],    gB0);
    async16(&Bs[0][w*32+16][0], gB1);
    __syncthreads();

    for (int kk = 0; kk < NK; ++kk) {
        const int cur = kk & 1;
        if (kk + 1 < NK) {
            const int k0 = (kk+1)*32;
            const int nx = cur ^ 1;
            async16(&As[nx][w*32][0],    gA0 + k0);
            async16(&As[nx][w*32+16][0], gA1 + k0);
            async16(&Bs[nx][w*32][0],    gB0 + k0);
            async16(&Bs[nx][w*32+16][0], gB1 + k0);
        }
        bf16x8 af[4], bfv[4];
#pragma unroll
        for (int i = 0; i < 4; ++i) {
            af[i]  = *(const bf16x8*)&As[cur][wr + i*16 + lc][quad*8];
            bfv[i] = *(const bf16x8*)&Bs[cur][wc + i*16 + lc][quad*8];
        }
#pragma unroll
        for (int mt = 0; mt < 4; ++mt)
#pragma unroll
            for (int nt = 0; nt < 4; ++nt)
                acc[mt][nt] = MFMA16(af[mt], bfv[nt], acc[mt][nt]);
        __syncthreads();
    }

    float bv[4];
#pragma unroll
    for (int nt = 0; nt < 4; ++nt) bv[nt] = bias[n0 + wc + nt*16 + lc];
#pragma unroll
    for (int mt = 0; mt < 4; ++mt) {
        const int row = m0 + wr + mt*16 + quad*4;
#pragma unroll
        for (int nt = 0; nt < 4; ++nt) {
            const int col = n0 + wc + nt*16 + lc;
#pragma unroll
            for (int r = 0; r < 4; ++r)
                outF[(size_t)(row+r)*1024 + col] = acc[mt][nt][r] + bv[nt];
        }
    }
}

// ---------------------------------------------------------------------------
// Flash attention, S^T formulation, no-max softmax, 128 q/block (2 strips).
// Round-10: SPLIT=4 with the R9-proven body — KVBLK=64, launch_bounds(256,4),
// natural VGPR=64 (R8 post-mortem: never force (256,8); the 64-cap spilled
// accumulators, FETCH 20MB->990MB). Grid (32,16,4)=2048 blocks -> 5 resident
// blocks/CU (LDS cap, was 4) on a latency-bound kernel. Same-bh blocks all
// land on one XCD (bh=blockIdx.x, XCD=bh%8) -> KV stays L2-local.
// Partials: bf16 half-normalized (R7/R8-proven numerics), 4-way combine.
// ---------------------------------------------------------------------------
template<int SPLIT>
__global__ __launch_bounds__(256, 4) void flash_attn_k(
    const ushort_t* __restrict__ Q, const ushort_t* __restrict__ Kg,
    const ushort_t* __restrict__ Vt, ushort_t* __restrict__ AO,
    ushort_t* __restrict__ PA, ushort_t* __restrict__ PB, float* __restrict__ Lp)
{
    constexpr int NJT = 64 / SPLIT;
    __shared__ ushort_t Ks[2][64][64];
    __shared__ ushort_t Vs[2][64][64];
    const int bh = blockIdx.x, qt = blockIdx.y;
    const int sp = (SPLIT > 1) ? (int)blockIdx.z : 0;
    const int jt0 = sp * NJT;
    const int b = bh>>3, h = bh&7;
    const int t = threadIdx.x, wv = t>>6, l = t&63;
    const int quad = l>>4, lc = l&15;

    const ushort_t* qbase = Q + ((size_t)bh*2048 + qt*128 + wv*16 + lc)*64;
    bf16x8 qA0 = *(const bf16x8*)(qbase + quad*8);
    bf16x8 qA1 = *(const bf16x8*)(qbase + 32 + quad*8);
    bf16x8 qB0 = *(const bf16x8*)(qbase + 64*64 + quad*8);
    bf16x8 qB1 = *(const bf16x8*)(qbase + 64*64 + 32 + quad*8);

    const ushort_t* Kb = Kg + (size_t)bh*4096*64;
    const ushort_t* Vb = Vt + (size_t)bh*64*4096;

    const int r8 = l>>3;
    const int sc = (l&7) ^ r8;
    const ushort_t* kg0 = Kb + ((size_t)jt0*64 + wv*16 + r8)*64 + sc*8;
    const ushort_t* kg1 = kg0 + (size_t)8*64;
    const ushort_t* vg0 = Vb + (size_t)(wv*16 + r8)*4096 + (size_t)jt0*64 + sc*8;
    const ushort_t* vg1 = vg0 + (size_t)8*4096;

    const int swA = ((quad       ^ (lc&7)) << 3);
    const int swB = (((quad ^ 4) ^ (lc&7)) << 3);

    float l0 = 0.0f, l1 = 0.0f;
    f32x4 o0[4] = {}, o1[4] = {};

    async16(&Ks[0][wv*16][0],   kg0);
    async16(&Ks[0][wv*16+8][0], kg1);
    async16(&Vs[0][wv*16][0],   vg0);
    async16(&Vs[0][wv*16+8][0], vg1);
    __syncthreads();

    for (int jt = 0; jt < NJT; ++jt) {
        const int cur = jt & 1;
        if (jt + 1 < NJT) {
            const int nx = cur ^ 1;
            const size_t ko = (size_t)(jt+1)*4096;   // 64 keys * 64 d
            const size_t vo = (size_t)(jt+1)*64;     // 64 keys
            async16(&Ks[nx][wv*16][0],   kg0 + ko);
            async16(&Ks[nx][wv*16+8][0], kg1 + ko);
            async16(&Vs[nx][wv*16][0],   vg0 + vo);
            async16(&Vs[nx][wv*16+8][0], vg1 + vo);
        }
        const ushort_t* KsC = &Ks[cur][0][0];
        const ushort_t* VsC = &Vs[cur][0][0];

        union { unsigned u[8]; bf16x8 v[2]; } p0, p1;
        float rs0 = 0.0f, rs1 = 0.0f;
#pragma unroll
        for (int kt = 0; kt < 4; ++kt) {
            const int ro = (kt*16 + lc)*64;
            bf16x8 kf0 = *(const bf16x8*)(KsC + ro + swA);
            bf16x8 kf1 = *(const bf16x8*)(KsC + ro + swB);
            f32x4 z0 = {}, z1 = {};
            __builtin_amdgcn_s_setprio(1);
            z0 = MFMA16(kf0, qA0, z0); z0 = MFMA16(kf1, qA1, z0);
            z1 = MFMA16(kf0, qB0, z1); z1 = MFMA16(kf1, qB1, z1);
            __builtin_amdgcn_s_setprio(0);
            float a0 = fexp2(z0[0]), a1v = fexp2(z0[1]);
            float a2 = fexp2(z0[2]), a3 = fexp2(z0[3]);
            rs0 += (a0 + a1v) + (a2 + a3);
            p0.u[kt*2]   = pack2bf(a0, a1v);
            p0.u[kt*2+1] = pack2bf(a2, a3);
            float c0 = fexp2(z1[0]), c1 = fexp2(z1[1]);
            float c2 = fexp2(z1[2]), c3 = fexp2(z1[3]);
            rs1 += (c0 + c1) + (c2 + c3);
            p1.u[kt*2]   = pack2bf(c0, c1);
            p1.u[kt*2+1] = pack2bf(c2, c3);
        }
        l0 += rs0; l1 += rs1;

#pragma unroll
        for (int dt = 0; dt < 4; ++dt) {
            const int ro = (dt*16 + lc)*64;
            bf16x8 vf0 = *(const bf16x8*)(VsC + ro + swA);
            bf16x8 vf1 = *(const bf16x8*)(VsC + ro + swB);
            __builtin_amdgcn_s_setprio(1);
            o0[dt] = MFMA16(vf0, p0.v[0], o0[dt]);
            o0[dt] = MFMA16(vf1, p0.v[1], o0[dt]);
            o1[dt] = MFMA16(vf0, p1.v[0], o1[dt]);
            o1[dt] = MFMA16(vf1, p1.v[1], o1[dt]);
            __builtin_amdgcn_s_setprio(0);
        }
        __syncthreads();
    }

    l0 += __shfl_xor(l0, 16); l0 += __shfl_xor(l0, 32);
    l1 += __shfl_xor(l1, 16); l1 += __shfl_xor(l1, 32);
    float li0 = 1.0f / l0, li1 = 1.0f / l1;

    if (SPLIT == 1) {
        const int qA = qt*128 + wv*16 + lc;
        ushort_t* aodA = AO + ((size_t)b*2048 + qA)*512 + h*64 + quad*4;
        ushort_t* aodB = aodA + (size_t)64*512;
#pragma unroll
        for (int dt = 0; dt < 4; ++dt) {
            uint2 oa, ob;
            oa.x = pack2bf(o0[dt][0]*li0, o0[dt][1]*li0);
            oa.y = pack2bf(o0[dt][2]*li0, o0[dt][3]*li0);
            *(uint2*)(aodA + dt*16) = oa;
            ob.x = pack2bf(o1[dt][0]*li1, o1[dt][1]*li1);
            ob.y = pack2bf(o1[dt][2]*li1, o1[dt][3]*li1);
            *(uint2*)(aodB + dt*16) = ob;
        }
    } else {
        // bf16 half-normalized partials + l; splits 0,1 in PA, 2,3 in PB
        ushort_t* P = (sp < 2) ? (PA + (size_t)sp*4194304)
                               : (PB + (size_t)(sp-2)*4194304);
        const int bid = bh*16 + qt;                 // 0..511
        const int qrA = wv*16 + lc;                 // strip-A q row (0..63)
        const size_t pbA = ((size_t)bid*128 + qrA)*64;
        const size_t pbB = pbA + (size_t)64*64;     // strip B at qrow+64
#pragma unroll
        for (int dt = 0; dt < 4; ++dt) {
            uint2 oa, ob;
            oa.x = pack2bf(o0[dt][0]*li0, o0[dt][1]*li0);
            oa.y = pack2bf(o0[dt][2]*li0, o0[dt][3]*li0);
            *(uint2*)(P + pbA + dt*16 + quad*4) = oa;
            ob.x = pack2bf(o1[dt][0]*li1, o1[dt][1]*li1);
            ob.y = pack2bf(o1[dt][2]*li1, o1[dt][3]*li1);
            *(uint2*)(P + pbB + dt*16 + quad*4) = ob;
        }
        if (l < 16) {   // quad 0 lanes hold lc == l; l fully reduced
            Lp[((size_t)sp*512 + bid)*128 + qrA]      = l0;
            Lp[((size_t)sp*512 + bid)*128 + 64 + qrA] = l1;
        }
    }
}

// ---------------------------------------------------------------------------
// Combine 4-way split partials (bf16, half-normalized; R8-proven numerics):
//   AO = sum_i w_i * O_i^n,  w_i = l_i / sum(l)   (fp32 merge, bf16 out)
// ---------------------------------------------------------------------------
__global__ __launch_bounds__(256) void combine_attn(
    const ushort_t* __restrict__ PA, const ushort_t* __restrict__ PB,
    const float* __restrict__ Lp, ushort_t* __restrict__ AO)
{
    const int bid = blockIdx.x;          // bh*16 + qt
    const int bh = bid>>4, qt = bid&15;
    const int b = bh>>3, h = bh&7;
    const int t = threadIdx.x;
    const int dcol = (t&15)*4;
    const size_t pblk = (size_t)bid*8192;
#pragma unroll
    for (int e = 0; e < 8; ++e) {
        const int qrow = e*16 + (t>>4);
        const size_t idx = pblk + (size_t)qrow*64 + dcol;
        uint2 u0 = *(const uint2*)(PA + idx);
        uint2 u1 = *(const uint2*)(PA + 4194304 + idx);
        uint2 u2 = *(const uint2*)(PB + idx);
        uint2 u3 = *(const uint2*)(PB + 4194304 + idx);
        float l0 = Lp[(size_t)(0*512 + bid)*128 + qrow];
        float l1 = Lp[(size_t)(1*512 + bid)*128 + qrow];
        float l2 = Lp[(size_t)(2*512 + bid)*128 + qrow];
        float l3 = Lp[(size_t)(3*512 + bid)*128 + qrow];
        float inv = 1.0f / (l0 + l1 + l2 + l3);
        float w0 = l0*inv, w1 = l1*inv, w2 = l2*inv, w3 = l3*inv;
        float r0 = w0*bflo(u0.x) + w1*bflo(u1.x) + w2*bflo(u2.x) + w3*bflo(u3.x);
        float r1 = w0*bfhi(u0.x) + w1*bfhi(u1.x) + w2*bfhi(u2.x) + w3*bfhi(u3.x);
        float r2 = w0*bflo(u0.y) + w1*bflo(u1.y) + w2*bflo(u2.y) + w3*bflo(u3.y);
        float r3 = w0*bfhi(u0.y) + w1*bfhi(u1.y) + w2*bfhi(u2.y) + w3*bfhi(u3.y);
        uint2 o;
        o.x = pack2bf(r0, r1);
        o.y = pack2bf(r2, r3);
        ushort_t* ao = AO + ((size_t)b*2048 + qt*128 + qrow)*512 + h*64 + dcol;
        *(uint2*)ao = o;
    }
}

// ---------------------------------------------------------------------------
extern "C" void kernel_launch(void* const* d_in, const int* in_sizes, int n_in,
                              void* d_out, int out_size, void* d_ws, size_t ws_size,
                              hipStream_t stream)
{
    const float* x1  = (const float*)d_in[0];
    const float* x2  = (const float*)d_in[1];
    const float* Wq1 = (const float*)d_in[2];
    const float* Wk1 = (const float*)d_in[3];
    const float* Wv1 = (const float*)d_in[4];
    const float* Wk2 = (const float*)d_in[5];
    const float* Wv2 = (const float*)d_in[6];
    const float* Wo  = (const float*)d_in[7];
    const float* bo  = (const float*)d_in[8];
    float* out = (float*)d_out;

    ushort_t* ws  = (ushort_t*)d_ws;
    ushort_t* Xc1 = ws;                 // 8,388,608 ush (reused: P splits 0,1)
    ushort_t* Xc2 = Xc1 + 8388608;      // 8,388,608 (reused as AO after attn)
    ushort_t* Wt1 = Xc2 + 8388608;      // 1,572,864 (dead after qkv -> L buffer)
    ushort_t* Wt2 = Wt1 + 1572864;      // 1,048,576
    ushort_t* Wot = Wt2 + 1048576;      //   524,288
    ushort_t* Qp  = Wot + 524288;       // 4,194,304
    ushort_t* Kp  = Qp  + 4194304;      // 8,388,608
    ushort_t* Vtp = Kp  + 8388608;      // 8,388,608  -> end 40,894,464 ush
    ushort_t* Pex = Vtp + 8388608;      // 8,388,608 (P splits 2,3)
    ushort_t* AOp = Xc2;

    prep_all<<<11008, 256, 0, stream>>>(x1, x2, Wq1, Wk1, Wv1, Wk2, Wv2, Wo,
                                        Xc1, Xc2, Wt1, Wt2, Wot);

    qkv_gemm<<<dim3(64,20), 256, 0, stream>>>(Xc1, Xc2, Wt1, Wt2, Qp, Kp, Vtp);

    const size_t NEED = 98566144ull;    // bytes: base 81.8MB + P23 16.8MB
    if (ws_size >= NEED) {
        ushort_t* P01 = Xc1;            // x1-bf16 dead after QKV gemms
        ushort_t* P23 = Pex;
        float*    Lf  = (float*)Wt1;    // Wt1 dead after qkv (1MB of 3MB)
        flash_attn_k<4><<<dim3(32,16,4), 256, 0, stream>>>(Qp, Kp, Vtp, nullptr, P01, P23, Lf);
        combine_attn<<<512, 256, 0, stream>>>(P01, P23, Lf, AOp);
    } else {
        flash_attn_k<1><<<dim3(32,16,1), 256, 0, stream>>>(Qp, Kp, Vtp, AOp, nullptr, nullptr, nullptr);
    }

    out_gemm<<<dim3(64,8), 256, 0, stream>>>(AOp, Wot, out, bo);
}